// Round 4
// baseline (353.592 us; speedup 1.0000x reference)
//
#include <hip/hip_runtime.h>
#include <hip/hip_bf16.h>
#include <stdint.h>

using bf16 = __hip_bfloat16;
typedef __bf16 bf16x8 __attribute__((ext_vector_type(8)));
typedef float f32x4 __attribute__((ext_vector_type(4)));
typedef unsigned short u16x8 __attribute__((ext_vector_type(8)));

// async global->LDS, 16B per lane: data lands at wave-uniform base + lane*16.
#define GLOAD_LDS16(gp, lp)                                                    \
  __builtin_amdgcn_global_load_lds(                                           \
      (const __attribute__((address_space(1))) void*)(gp),                     \
      (__attribute__((address_space(3))) void*)(lp), 16, 0, 0)

#define WAITCNT_VM(N) asm volatile("s_waitcnt vmcnt(" #N ")" ::: "memory")
#define WAITCNT_LGKM0() asm volatile("s_waitcnt lgkmcnt(0)" ::: "memory")

__device__ inline void store_out(bf16* p, float v)  { *p = __float2bfloat16(v); }
__device__ inline void store_out(float* p, float v) { *p = v; }

// ---------------------------------------------------------------------------
// NT GEMM, 256x256 tile, BK=32, 4-deep LDS ring (128 KB), counted vmcnt (T4),
// bank-swizzled LDS (T2, 0 conflicts measured), m201-style phase interleave
// (T3): each BK=32 step = 2 barrier-pair phases of 16 MFMA, + setprio (T5).
// C[m][n] = alpha * sum_k A[m][k] * Bt[n][k] (+bias).
// 512 threads = 8 waves (2M x 4N), per-wave output 128x64 (8x4 frags 16x16).
// Output column-split routing: cols [0,Nsplit) -> out0/bias0, rest out1/bias1.
// BIAS_AXIS: 0 = per-col, 1 = per-row. M,N mult of 256; K mult of 32, K/32>=4.
//
// LDS chunk layout per ring slot (A: elems [0,8192), B: [8192,16384)):
//   chunk idx (0..1023): slot=idx&7, r=2*(idx>>3)+(idx&1), c16=((slot^(r&7))>>1)
//   read side: elem(r,c16) = (r>>1)*64 + ((r&7)^(c16<<1))*8   [2-way banks=free]
// Sync per K-step j (phases A,B):
//   A: 8 ds_read (afm0-3,bf n0-3); stage 2 chunks(tile j+3); bar; lgkm0; 16 MFMA; bar
//   B: 4 ds_read (af m4-7);        stage 2 chunks(tile j+3); bar; lgkm0; 16 MFMA;
//      vmcnt(8) [tile j+1 resident after barrier]; bar
// Slot safety: stage slot (j+3)&3 last read at step j-1; those reads drained
// (lgkm0) before step j-1's final barrier; stages issued after it.
// ---------------------------------------------------------------------------
template <typename OUT_T, int BIAS_AXIS>
__global__ __launch_bounds__(512, 2) void gemm256(
    const bf16* __restrict__ A, const bf16* __restrict__ Bt,
    const float* __restrict__ bias0, const float* __restrict__ bias1,
    OUT_T* __restrict__ out0, OUT_T* __restrict__ out1, int Nsplit,
    int K, int lda, int ldb, int ldc,
    long long sA, long long sB, long long sC, float alpha)
{
    __shared__ __align__(16) bf16 lds[4 * 16384];   // 4 ring slots x 32 KB

    const int z = blockIdx.z;
    A  += (long long)z * sA;
    Bt += (long long)z * sB;
    out0 += (long long)z * sC;
    if (out1) out1 += (long long)z * sC;

    const int bm = blockIdx.x * 256;
    const int bn = blockIdx.y * 256;
    const int t = threadIdx.x, lane = t & 63, w = t >> 6;
    const int wm = w >> 2, wn = w & 3;            // wave tile coords (2 x 4)
    const int fr = lane & 15, c16 = lane >> 4;

    // ---- staging precompute: 4 chunks/thread (2 A, 2 B), inverse-swizzled src
    const bf16* gsrc[4];
    int lbase[4];
    #pragma unroll
    for (int c = 0; c < 4; ++c) {
        const int idx  = w * 128 + (c & 1) * 64 + lane;    // chunk in half
        const int slot = idx & 7;
        const int r    = ((idx >> 3) << 1) | (idx & 1);
        const int cc   = (slot ^ (r & 7)) >> 1;            // 0..3
        if (c < 2) {
            gsrc[c]  = A + (long long)(bm + r) * lda + cc * 8;
            lbase[c] = w * 1024 + c * 512;
        } else {
            gsrc[c]  = Bt + (long long)(bn + r) * ldb + cc * 8;
            lbase[c] = 8192 + w * 1024 + (c - 2) * 512;
        }
    }

    // ---- fragment read offsets (elements), swizzled
    const int sw   = ((fr & 7) ^ (c16 << 1)) * 8;
    const int offA = (wm * 64 + (fr >> 1)) * 64 + sw;          // + m*512
    const int offB = 8192 + (wn * 32 + (fr >> 1)) * 64 + sw;   // + n*512

    const int nk = K >> 5;

    auto STAGE2 = [&](int jt, int h) {      // h=0: A chunks, h=1: B chunks
        const int buf = (jt & 3) * 16384;
        GLOAD_LDS16(gsrc[2 * h]     + jt * 32, &lds[buf + lbase[2 * h]]);
        GLOAD_LDS16(gsrc[2 * h + 1] + jt * 32, &lds[buf + lbase[2 * h + 1]]);
    };

    // prologue: stage tiles 0,1,2 (12 loads); ensure tile 0 landed block-wide
    STAGE2(0, 0); STAGE2(0, 1);
    STAGE2(1, 0); STAGE2(1, 1);
    STAGE2(2, 0); STAGE2(2, 1);
    WAITCNT_VM(8);
    __builtin_amdgcn_s_barrier();

    f32x4 acc[8][4] = {};

    for (int j = 0; j < nk; ++j) {
        const int buf = (j & 3) * 16384;
        const bool pref = (j + 3 < nk);

        // ================= phase A: quadrant m0-3 x n0-3 =================
        bf16x8 af[4], bfv[4], af2[4];
        #pragma unroll
        for (int m = 0; m < 4; ++m)
            af[m] = *reinterpret_cast<const bf16x8*>(&lds[buf + offA + m * 512]);
        #pragma unroll
        for (int n = 0; n < 4; ++n)
            bfv[n] = *reinterpret_cast<const bf16x8*>(&lds[buf + offB + n * 512]);
        if (pref) STAGE2(j + 3, 0);

        __builtin_amdgcn_s_barrier();
        WAITCNT_LGKM0();
        __builtin_amdgcn_sched_barrier(0);   // rule 18: pin MFMAs below the wait
        __builtin_amdgcn_s_setprio(1);
        #pragma unroll
        for (int m = 0; m < 4; ++m)
            #pragma unroll
            for (int n = 0; n < 4; ++n)
                acc[m][n] = __builtin_amdgcn_mfma_f32_16x16x32_bf16(
                    af[m], bfv[n], acc[m][n], 0, 0, 0);
        __builtin_amdgcn_s_setprio(0);
        __builtin_amdgcn_sched_barrier(0);
        __builtin_amdgcn_s_barrier();

        // ================= phase B: quadrant m4-7 x n0-3 =================
        #pragma unroll
        for (int m = 0; m < 4; ++m)
            af2[m] = *reinterpret_cast<const bf16x8*>(
                &lds[buf + offA + (m + 4) * 512]);
        if (pref) STAGE2(j + 3, 1);

        __builtin_amdgcn_s_barrier();
        WAITCNT_LGKM0();
        __builtin_amdgcn_sched_barrier(0);
        __builtin_amdgcn_s_setprio(1);
        #pragma unroll
        for (int m = 0; m < 4; ++m)
            #pragma unroll
            for (int n = 0; n < 4; ++n)
                acc[m + 4][n] = __builtin_amdgcn_mfma_f32_16x16x32_bf16(
                    af2[m], bfv[n], acc[m + 4][n], 0, 0, 0);
        __builtin_amdgcn_s_setprio(0);
        __builtin_amdgcn_sched_barrier(0);

        // counted drain: tile j+1 fully in LDS after this barrier (never 0
        // until the 2-step tail)
        if (j + 3 < nk)      { WAITCNT_VM(8); }
        else if (j + 2 < nk) { WAITCNT_VM(4); }
        else if (j + 1 < nk) { WAITCNT_VM(0); }
        __builtin_amdgcn_s_barrier();
    }

    // ---- epilogue: C/D layout col = lane&15, row = 4*(lane>>4)+reg
    const int colbase = bn + wn * 64 + fr;
    const int rowbase = bm + wm * 128 + c16 * 4;
    #pragma unroll
    for (int n = 0; n < 4; ++n) {
        const int gc = colbase + n * 16;
        const bool seg0 = gc < Nsplit;
        OUT_T* op = seg0 ? out0 : out1;
        const int col = seg0 ? gc : gc - Nsplit;
        float bcol = 0.0f;
        if (BIAS_AXIS == 0) {
            const float* bp = seg0 ? bias0 : bias1;
            if (bp) bcol = bp[col];
        }
        #pragma unroll
        for (int m = 0; m < 8; ++m) {
            #pragma unroll
            for (int jj = 0; jj < 4; ++jj) {
                const int row = rowbase + m * 16 + jj;
                float v = acc[m][n][jj] * alpha;
                if (BIAS_AXIS == 0) v += bcol;
                else if (bias0)     v += bias0[row];
                store_out(&op[(long long)row * ldc + col], v);
            }
        }
    }
}

// ---------------------------------------------------------------------------
// fp32 -> bf16 elementwise convert (n multiple of 4)
// ---------------------------------------------------------------------------
__global__ __launch_bounds__(256) void f32_to_bf16(
    const float* __restrict__ in, bf16* __restrict__ out, long long n)
{
    long long i = ((long long)blockIdx.x * 256 + threadIdx.x) * 4;
    const long long stride = (long long)gridDim.x * 256 * 4;
    for (; i < n; i += stride) {
        float4 v = *reinterpret_cast<const float4*>(in + i);
        unsigned ux = __float_as_uint(v.x), uy = __float_as_uint(v.y);
        unsigned uz = __float_as_uint(v.z), uw = __float_as_uint(v.w);
        ushort4 o;
        o.x = (unsigned short)((ux + 0x7fffu + ((ux >> 16) & 1u)) >> 16);
        o.y = (unsigned short)((uy + 0x7fffu + ((uy >> 16) & 1u)) >> 16);
        o.z = (unsigned short)((uz + 0x7fffu + ((uz >> 16) & 1u)) >> 16);
        o.w = (unsigned short)((uw + 0x7fffu + ((uw >> 16) & 1u)) >> 16);
        *reinterpret_cast<ushort4*>(out + i) = o;
    }
}

// ---------------------------------------------------------------------------
// Transpose fp32 in [R][C] -> bf16 out [C][R]
// ---------------------------------------------------------------------------
__global__ void transpose_f32_bf16(const float* __restrict__ in,
                                   bf16* __restrict__ out, int R, int C)
{
    __shared__ float tile[32][33];
    const int c0 = blockIdx.x * 32, r0 = blockIdx.y * 32;
    const int tx = threadIdx.x, ty = threadIdx.y;
    #pragma unroll
    for (int i = ty; i < 32; i += 8)
        tile[i][tx] = in[(long long)(r0 + i) * C + (c0 + tx)];
    __syncthreads();
    #pragma unroll
    for (int i = ty; i < 32; i += 8)
        out[(long long)(c0 + i) * R + (r0 + tx)] = __float2bfloat16(tile[tx][i]);
}

// ---------------------------------------------------------------------------
// Row softmax, in-place on bf16 buffer, one 256-thread block per 2048-col row.
// ---------------------------------------------------------------------------
__global__ __launch_bounds__(256) void softmax_rows(bf16* __restrict__ Sbuf, int cols)
{
    __shared__ float red[8];
    bf16* p = Sbuf + (long long)blockIdx.x * cols;
    const int t = threadIdx.x;

    u16x8 v = *reinterpret_cast<const u16x8*>(p + t * 8);
    float f[8];
    #pragma unroll
    for (int i = 0; i < 8; ++i)
        f[i] = __uint_as_float((unsigned)v[i] << 16);

    float m = -3.0e38f;
    #pragma unroll
    for (int i = 0; i < 8; ++i) m = fmaxf(m, f[i]);
    #pragma unroll
    for (int o = 32; o; o >>= 1) m = fmaxf(m, __shfl_xor(m, o));
    if ((t & 63) == 0) red[t >> 6] = m;
    __syncthreads();
    m = fmaxf(fmaxf(red[0], red[1]), fmaxf(red[2], red[3]));

    float s = 0.0f;
    #pragma unroll
    for (int i = 0; i < 8; ++i) { f[i] = __expf(f[i] - m); s += f[i]; }
    #pragma unroll
    for (int o = 32; o; o >>= 1) s += __shfl_xor(s, o);
    __syncthreads();
    if ((t & 63) == 0) red[4 + (t >> 6)] = s;
    __syncthreads();
    s = (red[4] + red[5]) + (red[6] + red[7]);
    const float inv = 1.0f / s;

    u16x8 o16;
    #pragma unroll
    for (int i = 0; i < 8; ++i) {
        unsigned u = __float_as_uint(f[i] * inv);
        o16[i] = (unsigned short)((u + 0x7fffu + ((u >> 16) & 1u)) >> 16);  // RNE
    }
    *reinterpret_cast<u16x8*>(p + t * 8) = o16;
}

// ---------------------------------------------------------------------------
extern "C" void kernel_launch(void* const* d_in, const int* in_sizes, int n_in,
                              void* d_out, int out_size, void* d_ws, size_t ws_size,
                              hipStream_t stream)
{
    const int B = 8, S = 2048, D = 1024, H = 1024;
    const float* x  = (const float*)d_in[0];
    const float* Wq = (const float*)d_in[1];
    const float* bq = (const float*)d_in[2];
    const float* Wk = (const float*)d_in[3];
    const float* bk = (const float*)d_in[4];
    const float* Wv = (const float*)d_in[5];
    const float* bv = (const float*)d_in[6];
    float* out = (float*)d_out;

    const size_t nQKV = (size_t)B * S * H;   // 16.78M
    const size_t nW   = (size_t)D * H;       // 1.05M
    const long long sSH = (long long)S * H;
    const long long sSS = (long long)S * S;

    dim3 tb(32, 8), g256(256), g512(512);
    const float inv_scale = 1.0f / 32.0f;    // 1/sqrt(H)

    // ws: xb | Q | K | Vt | WtQK(2nW) | Wtv(nW) | Sc
    bf16* xb   = (bf16*)d_ws;
    bf16* Q    = xb  + nQKV;
    bf16* Kb   = Q   + nQKV;
    bf16* Vt   = Kb  + nQKV;                 // [H][B*S], ld = B*S
    bf16* WtQK = Vt  + nQKV;
    bf16* Wtv  = WtQK + 2 * nW;
    bf16* Sc   = Wtv + nW;

    const size_t tierA = (4 * nQKV + 3 * nW + (size_t)B * S * S) * 2;
    const size_t tierB = (4 * nQKV + 3 * nW + (size_t)S * S) * 2;
    const bool bigA = ws_size >= tierA;
    if (ws_size < tierB) return;

    // 1. convert x; transpose weights (Wq|Wk -> WtQK rows 0..2047, Wv -> Wtv)
    f32_to_bf16<<<dim3(2048), g256, 0, stream>>>(x, xb, (long long)nQKV);
    transpose_f32_bf16<<<dim3(H / 32, D / 32), tb, 0, stream>>>(Wq, WtQK, D, H);
    transpose_f32_bf16<<<dim3(H / 32, D / 32), tb, 0, stream>>>(Wk, WtQK + nW, D, H);
    transpose_f32_bf16<<<dim3(H / 32, D / 32), tb, 0, stream>>>(Wv, Wtv, D, H);

    // 2. fused Q|K projection: [B*S,1024] x [2048,1024]^T -> Q, K (col-split)
    gemm256<bf16, 0><<<dim3(B * S / 256, 2 * H / 256, 1), g512, 0, stream>>>(
        xb, WtQK, bq, bk, Q, Kb, H, D, D, D, H, 0, 0, 0, 1.0f);

    // 3. V^T = Wv^T x^T : A=Wtv [H][D], Bt=xb [B*S][D] -> Vt [H][B*S], bias-by-row
    gemm256<bf16, 1><<<dim3(H / 256, B * S / 256, 1), g512, 0, stream>>>(
        Wtv, xb, bv, nullptr, Vt, nullptr, 1 << 30, D, D, D, B * S, 0, 0, 0, 1.0f);

    if (bigA) {
        // 4. scores = Q K^T / 32, batched
        gemm256<bf16, 0><<<dim3(S / 256, S / 256, B), g512, 0, stream>>>(
            Q, Kb, nullptr, nullptr, Sc, nullptr, 1 << 30, H, H, H, S,
            sSH, sSH, sSS, inv_scale);
        // 5. softmax rows in place
        softmax_rows<<<dim3(B * S), g256, 0, stream>>>(Sc, S);
        // 6. out = P V : A=Sc [S][S], Bt=Vt(+b*S) [H][B*S] -> out [S][H] fp32
        gemm256<float, 0><<<dim3(S / 256, H / 256, B), g512, 0, stream>>>(
            Sc, Vt, nullptr, nullptr, out, nullptr, 1 << 30, S, S, B * S, H,
            sSS, (long long)S, sSH, 1.0f);
    } else {
        for (int b = 0; b < B; ++b) {
            gemm256<bf16, 0><<<dim3(S / 256, S / 256, 1), g512, 0, stream>>>(
                Q + (size_t)b * sSH, Kb + (size_t)b * sSH, nullptr, nullptr,
                Sc, nullptr, 1 << 30, H, H, H, S, 0, 0, 0, inv_scale);
            softmax_rows<<<dim3(S), g256, 0, stream>>>(Sc, S);
            gemm256<float, 0><<<dim3(S / 256, H / 256, 1), g512, 0, stream>>>(
                Sc, Vt + (size_t)b * S, nullptr, nullptr,
                out + (size_t)b * sSH, nullptr, 1 << 30, S, S, B * S, H,
                0, 0, 0, 1.0f);
        }
    }
}

// Round 5
// 351.575 us; speedup vs baseline: 1.0057x; 1.0057x over previous
//
#include <hip/hip_runtime.h>
#include <hip/hip_bf16.h>
#include <stdint.h>

using bf16 = __hip_bfloat16;
typedef __bf16 bf16x8 __attribute__((ext_vector_type(8)));
typedef float f32x4 __attribute__((ext_vector_type(4)));
typedef unsigned short u16x8 __attribute__((ext_vector_type(8)));

// async global->LDS, 16B per lane: data lands at wave-uniform base + lane*16.
#define GLOAD_LDS16(gp, lp)                                                    \
  __builtin_amdgcn_global_load_lds(                                           \
      (const __attribute__((address_space(1))) void*)(gp),                     \
      (__attribute__((address_space(3))) void*)(lp), 16, 0, 0)

#define WAITCNT_VM(N) asm volatile("s_waitcnt vmcnt(" #N ")" ::: "memory")
#define WAITCNT_LGKM0() asm volatile("s_waitcnt lgkmcnt(0)" ::: "memory")

__device__ inline void store_out(bf16* p, float v)  { *p = __float2bfloat16(v); }
__device__ inline void store_out(float* p, float v) { *p = v; }

// ---------------------------------------------------------------------------
// NT GEMM, 256x256 tile, BK=32, 4-deep LDS ring (128 KB), counted vmcnt (T4),
// bank-swizzled LDS (T2, 0 conflicts measured), 2 barrier-phases per K-step,
// setprio (T5), and NEW: T1 chunked-XCD block swizzle with panel-sharing
// logical order (NFAST: true = nt-fastest within chunk, false = mt-fastest).
// C[m][n] = alpha * sum_k A[m][k] * Bt[n][k] (+bias).
// 512 threads = 8 waves (2M x 4N), per-wave output 128x64 (8x4 frags 16x16).
// Output column-split routing: cols [0,Nsplit) -> out0/bias0, rest out1/bias1.
// BIAS_AXIS: 0 = per-col, 1 = per-row. M,N mult of 256; K mult of 32, K/32>=4.
//
// LDS chunk layout per ring slot (A: elems [0,8192), B: [8192,16384)):
//   chunk idx (0..1023): slot=idx&7, r=2*(idx>>3)+(idx&1), c16=((slot^(r&7))>>1)
//   read side: elem(r,c16) = (r>>1)*64 + ((r&7)^(c16<<1))*8   [2-way banks=free]
// Sync per K-step j (phases A,B):
//   A: 8 ds_read (af m0-3, bf n0-3); stage A-chunks(tile j+3); bar; lgkm0;
//      16 MFMA; bar
//   B: 4 ds_read (af m4-7);          stage B-chunks(tile j+3); bar; lgkm0;
//      16 MFMA; vmcnt(8) [tile j+1 resident after barrier]; bar
// Slot safety: stage slot (j+3)&3 last read at step j-1; those reads drained
// (lgkm0) before step j-1's final barrier; stages issued after it.
// XCD swizzle: HW round-robins linear block id across 8 XCDs; lg =
// (hw%8)*(nwg/8)+hw/8 gives each XCD a contiguous chunk of logical tiles, so
// shared A/B panels within the chunk stay in that XCD's 4MB L2.
// ---------------------------------------------------------------------------
template <typename OUT_T, int BIAS_AXIS, bool NFAST>
__global__ __launch_bounds__(512, 2) void gemm256(
    const bf16* __restrict__ A, const bf16* __restrict__ Bt,
    const float* __restrict__ bias0, const float* __restrict__ bias1,
    OUT_T* __restrict__ out0, OUT_T* __restrict__ out1, int Nsplit,
    int K, int lda, int ldb, int ldc,
    long long sA, long long sB, long long sC, float alpha)
{
    __shared__ __align__(16) bf16 lds[4 * 16384];   // 4 ring slots x 32 KB

    // ---- T1: chunked XCD swizzle + logical tile decode
    const int Mt = gridDim.x, Nt = gridDim.y;
    const int nwg = Mt * Nt * gridDim.z;
    const int hw  = blockIdx.x + Mt * (blockIdx.y + Nt * blockIdx.z);
    const int lg  = (nwg & 7) ? hw : ((hw & 7) * (nwg >> 3) + (hw >> 3));
    const int per = Mt * Nt;
    const int zt  = lg / per;
    const int rem = lg - zt * per;
    int mt, nt;
    if (NFAST) { mt = rem / Nt; nt = rem - mt * Nt; }
    else       { mt = rem % Mt; nt = rem / Mt; }

    A  += (long long)zt * sA;
    Bt += (long long)zt * sB;
    out0 += (long long)zt * sC;
    if (out1) out1 += (long long)zt * sC;

    const int bm = mt * 256;
    const int bn = nt * 256;
    const int t = threadIdx.x, lane = t & 63, w = t >> 6;
    const int wm = w >> 2, wn = w & 3;            // wave tile coords (2 x 4)
    const int fr = lane & 15, c16 = lane >> 4;

    // ---- staging precompute: 4 chunks/thread (2 A, 2 B), inverse-swizzled src
    const bf16* gsrc[4];
    int lbase[4];
    #pragma unroll
    for (int c = 0; c < 4; ++c) {
        const int idx  = w * 128 + (c & 1) * 64 + lane;    // chunk in half
        const int slot = idx & 7;
        const int r    = ((idx >> 3) << 1) | (idx & 1);
        const int cc   = (slot ^ (r & 7)) >> 1;            // 0..3
        if (c < 2) {
            gsrc[c]  = A + (long long)(bm + r) * lda + cc * 8;
            lbase[c] = w * 1024 + c * 512;
        } else {
            gsrc[c]  = Bt + (long long)(bn + r) * ldb + cc * 8;
            lbase[c] = 8192 + w * 1024 + (c - 2) * 512;
        }
    }

    // ---- fragment read offsets (elements), swizzled
    const int sw   = ((fr & 7) ^ (c16 << 1)) * 8;
    const int offA = (wm * 64 + (fr >> 1)) * 64 + sw;          // + m*512
    const int offB = 8192 + (wn * 32 + (fr >> 1)) * 64 + sw;   // + n*512

    const int nk = K >> 5;

    auto STAGE2 = [&](int jt, int h) {      // h=0: A chunks, h=1: B chunks
        const int buf = (jt & 3) * 16384;
        GLOAD_LDS16(gsrc[2 * h]     + jt * 32, &lds[buf + lbase[2 * h]]);
        GLOAD_LDS16(gsrc[2 * h + 1] + jt * 32, &lds[buf + lbase[2 * h + 1]]);
    };

    // prologue: stage tiles 0,1,2 (12 loads); ensure tile 0 landed block-wide
    STAGE2(0, 0); STAGE2(0, 1);
    STAGE2(1, 0); STAGE2(1, 1);
    STAGE2(2, 0); STAGE2(2, 1);
    WAITCNT_VM(8);
    __builtin_amdgcn_s_barrier();

    f32x4 acc[8][4] = {};

    for (int j = 0; j < nk; ++j) {
        const int buf = (j & 3) * 16384;
        const bool pref = (j + 3 < nk);

        // ================= phase A: quadrant m0-3 x n0-3 =================
        bf16x8 af[4], bfv[4], af2[4];
        #pragma unroll
        for (int m = 0; m < 4; ++m)
            af[m] = *reinterpret_cast<const bf16x8*>(&lds[buf + offA + m * 512]);
        #pragma unroll
        for (int n = 0; n < 4; ++n)
            bfv[n] = *reinterpret_cast<const bf16x8*>(&lds[buf + offB + n * 512]);
        if (pref) STAGE2(j + 3, 0);

        __builtin_amdgcn_s_barrier();
        WAITCNT_LGKM0();
        __builtin_amdgcn_sched_barrier(0);   // rule 18: pin MFMAs below the wait
        __builtin_amdgcn_s_setprio(1);
        #pragma unroll
        for (int m = 0; m < 4; ++m)
            #pragma unroll
            for (int n = 0; n < 4; ++n)
                acc[m][n] = __builtin_amdgcn_mfma_f32_16x16x32_bf16(
                    af[m], bfv[n], acc[m][n], 0, 0, 0);
        __builtin_amdgcn_s_setprio(0);
        __builtin_amdgcn_sched_barrier(0);
        __builtin_amdgcn_s_barrier();

        // ================= phase B: quadrant m4-7 x n0-3 =================
        #pragma unroll
        for (int m = 0; m < 4; ++m)
            af2[m] = *reinterpret_cast<const bf16x8*>(
                &lds[buf + offA + (m + 4) * 512]);
        if (pref) STAGE2(j + 3, 1);

        __builtin_amdgcn_s_barrier();
        WAITCNT_LGKM0();
        __builtin_amdgcn_sched_barrier(0);
        __builtin_amdgcn_s_setprio(1);
        #pragma unroll
        for (int m = 0; m < 4; ++m)
            #pragma unroll
            for (int n = 0; n < 4; ++n)
                acc[m + 4][n] = __builtin_amdgcn_mfma_f32_16x16x32_bf16(
                    af2[m], bfv[n], acc[m + 4][n], 0, 0, 0);
        __builtin_amdgcn_s_setprio(0);
        __builtin_amdgcn_sched_barrier(0);

        // counted drain: tile j+1 fully in LDS after this barrier (never 0
        // until the 2-step tail)
        if (j + 3 < nk)      { WAITCNT_VM(8); }
        else if (j + 2 < nk) { WAITCNT_VM(4); }
        else if (j + 1 < nk) { WAITCNT_VM(0); }
        __builtin_amdgcn_s_barrier();
    }

    // ---- epilogue: C/D layout col = lane&15, row = 4*(lane>>4)+reg
    const int colbase = bn + wn * 64 + fr;
    const int rowbase = bm + wm * 128 + c16 * 4;
    #pragma unroll
    for (int n = 0; n < 4; ++n) {
        const int gc = colbase + n * 16;
        const bool seg0 = gc < Nsplit;
        OUT_T* op = seg0 ? out0 : out1;
        const int col = seg0 ? gc : gc - Nsplit;
        float bcol = 0.0f;
        if (BIAS_AXIS == 0) {
            const float* bp = seg0 ? bias0 : bias1;
            if (bp) bcol = bp[col];
        }
        #pragma unroll
        for (int m = 0; m < 8; ++m) {
            #pragma unroll
            for (int jj = 0; jj < 4; ++jj) {
                const int row = rowbase + m * 16 + jj;
                float v = acc[m][n][jj] * alpha;
                if (BIAS_AXIS == 0) v += bcol;
                else if (bias0)     v += bias0[row];
                store_out(&op[(long long)row * ldc + col], v);
            }
        }
    }
}

// ---------------------------------------------------------------------------
// fp32 -> bf16 elementwise convert (n multiple of 4)
// ---------------------------------------------------------------------------
__global__ __launch_bounds__(256) void f32_to_bf16(
    const float* __restrict__ in, bf16* __restrict__ out, long long n)
{
    long long i = ((long long)blockIdx.x * 256 + threadIdx.x) * 4;
    const long long stride = (long long)gridDim.x * 256 * 4;
    for (; i < n; i += stride) {
        float4 v = *reinterpret_cast<const float4*>(in + i);
        unsigned ux = __float_as_uint(v.x), uy = __float_as_uint(v.y);
        unsigned uz = __float_as_uint(v.z), uw = __float_as_uint(v.w);
        ushort4 o;
        o.x = (unsigned short)((ux + 0x7fffu + ((ux >> 16) & 1u)) >> 16);
        o.y = (unsigned short)((uy + 0x7fffu + ((uy >> 16) & 1u)) >> 16);
        o.z = (unsigned short)((uz + 0x7fffu + ((uz >> 16) & 1u)) >> 16);
        o.w = (unsigned short)((uw + 0x7fffu + ((uw >> 16) & 1u)) >> 16);
        *reinterpret_cast<ushort4*>(out + i) = o;
    }
}

// ---------------------------------------------------------------------------
// Transpose fp32 in [R][C] -> bf16 out [C][R]
// ---------------------------------------------------------------------------
__global__ void transpose_f32_bf16(const float* __restrict__ in,
                                   bf16* __restrict__ out, int R, int C)
{
    __shared__ float tile[32][33];
    const int c0 = blockIdx.x * 32, r0 = blockIdx.y * 32;
    const int tx = threadIdx.x, ty = threadIdx.y;
    #pragma unroll
    for (int i = ty; i < 32; i += 8)
        tile[i][tx] = in[(long long)(r0 + i) * C + (c0 + tx)];
    __syncthreads();
    #pragma unroll
    for (int i = ty; i < 32; i += 8)
        out[(long long)(c0 + i) * R + (r0 + tx)] = __float2bfloat16(tile[tx][i]);
}

// ---------------------------------------------------------------------------
// Row softmax, in-place on bf16 buffer, one 256-thread block per 2048-col row.
// ---------------------------------------------------------------------------
__global__ __launch_bounds__(256) void softmax_rows(bf16* __restrict__ Sbuf, int cols)
{
    __shared__ float red[8];
    bf16* p = Sbuf + (long long)blockIdx.x * cols;
    const int t = threadIdx.x;

    u16x8 v = *reinterpret_cast<const u16x8*>(p + t * 8);
    float f[8];
    #pragma unroll
    for (int i = 0; i < 8; ++i)
        f[i] = __uint_as_float((unsigned)v[i] << 16);

    float m = -3.0e38f;
    #pragma unroll
    for (int i = 0; i < 8; ++i) m = fmaxf(m, f[i]);
    #pragma unroll
    for (int o = 32; o; o >>= 1) m = fmaxf(m, __shfl_xor(m, o));
    if ((t & 63) == 0) red[t >> 6] = m;
    __syncthreads();
    m = fmaxf(fmaxf(red[0], red[1]), fmaxf(red[2], red[3]));

    float s = 0.0f;
    #pragma unroll
    for (int i = 0; i < 8; ++i) { f[i] = __expf(f[i] - m); s += f[i]; }
    #pragma unroll
    for (int o = 32; o; o >>= 1) s += __shfl_xor(s, o);
    __syncthreads();
    if ((t & 63) == 0) red[4 + (t >> 6)] = s;
    __syncthreads();
    s = (red[4] + red[5]) + (red[6] + red[7]);
    const float inv = 1.0f / s;

    u16x8 o16;
    #pragma unroll
    for (int i = 0; i < 8; ++i) {
        unsigned u = __float_as_uint(f[i] * inv);
        o16[i] = (unsigned short)((u + 0x7fffu + ((u >> 16) & 1u)) >> 16);  // RNE
    }
    *reinterpret_cast<u16x8*>(p + t * 8) = o16;
}

// ---------------------------------------------------------------------------
extern "C" void kernel_launch(void* const* d_in, const int* in_sizes, int n_in,
                              void* d_out, int out_size, void* d_ws, size_t ws_size,
                              hipStream_t stream)
{
    const int B = 8, S = 2048, D = 1024, H = 1024;
    const float* x  = (const float*)d_in[0];
    const float* Wq = (const float*)d_in[1];
    const float* bq = (const float*)d_in[2];
    const float* Wk = (const float*)d_in[3];
    const float* bk = (const float*)d_in[4];
    const float* Wv = (const float*)d_in[5];
    const float* bv = (const float*)d_in[6];
    float* out = (float*)d_out;

    const size_t nQKV = (size_t)B * S * H;   // 16.78M
    const size_t nW   = (size_t)D * H;       // 1.05M
    const long long sSH = (long long)S * H;
    const long long sSS = (long long)S * S;

    dim3 tb(32, 8), g256(256), g512(512);
    const float inv_scale = 1.0f / 32.0f;    // 1/sqrt(H)

    // ws: xb | Q | K | Vt | WtQK(2nW) | Wtv(nW) | Sc
    bf16* xb   = (bf16*)d_ws;
    bf16* Q    = xb  + nQKV;
    bf16* Kb   = Q   + nQKV;
    bf16* Vt   = Kb  + nQKV;                 // [H][B*S], ld = B*S
    bf16* WtQK = Vt  + nQKV;
    bf16* Wtv  = WtQK + 2 * nW;
    bf16* Sc   = Wtv + nW;

    const size_t tierA = (4 * nQKV + 3 * nW + (size_t)B * S * S) * 2;
    const size_t tierB = (4 * nQKV + 3 * nW + (size_t)S * S) * 2;
    const bool bigA = ws_size >= tierA;
    if (ws_size < tierB) return;

    // 1. convert x; transpose weights (Wq|Wk -> WtQK rows 0..2047, Wv -> Wtv)
    f32_to_bf16<<<dim3(2048), g256, 0, stream>>>(x, xb, (long long)nQKV);
    transpose_f32_bf16<<<dim3(H / 32, D / 32), tb, 0, stream>>>(Wq, WtQK, D, H);
    transpose_f32_bf16<<<dim3(H / 32, D / 32), tb, 0, stream>>>(Wk, WtQK + nW, D, H);
    transpose_f32_bf16<<<dim3(H / 32, D / 32), tb, 0, stream>>>(Wv, Wtv, D, H);

    // 2. fused Q|K projection: [B*S,1024] x [2048,1024]^T -> Q, K (col-split)
    //    NFAST: chunk = 8 mt x 8 nt; xb panel reused x8, WtQK L2-resident.
    gemm256<bf16, 0, true><<<dim3(B * S / 256, 2 * H / 256, 1), g512, 0, stream>>>(
        xb, WtQK, bq, bk, Q, Kb, H, D, D, D, H, 0, 0, 0, 1.0f);

    // 3. V^T = Wv^T x^T : A=Wtv [H][D], Bt=xb [B*S][D] -> Vt [H][B*S], bias-by-row
    //    M-fast: chunk = 8 nt x 4 mt; xb panel reused x4, Wtv (2MB) resident.
    gemm256<bf16, 1, false><<<dim3(H / 256, B * S / 256, 1), g512, 0, stream>>>(
        Wtv, xb, bv, nullptr, Vt, nullptr, 1 << 30, D, D, D, B * S, 0, 0, 0, 1.0f);

    if (bigA) {
        // 4. scores = Q K^T / 32, batched; chunk = one batch per XCD,
        //    nt-fastest: Q panel reused x8, Kb (4MB) L2-resident.
        gemm256<bf16, 0, true><<<dim3(S / 256, S / 256, B), g512, 0, stream>>>(
            Q, Kb, nullptr, nullptr, Sc, nullptr, 1 << 30, H, H, H, S,
            sSH, sSH, sSS, inv_scale);
        // 5. softmax rows in place
        softmax_rows<<<dim3(B * S), g256, 0, stream>>>(Sc, S);
        // 6. out = P V : A=Sc [S][S], Bt=Vt(+b*S) [H][B*S] -> out [S][H] fp32
        //    chunk = one batch, nt-fastest: Sc panel reused x4, Vt resident.
        gemm256<float, 0, true><<<dim3(S / 256, H / 256, B), g512, 0, stream>>>(
            Sc, Vt, nullptr, nullptr, out, nullptr, 1 << 30, S, S, B * S, H,
            sSS, (long long)S, sSH, 1.0f);
    } else {
        for (int b = 0; b < B; ++b) {
            gemm256<bf16, 0, true><<<dim3(S / 256, S / 256, 1), g512, 0, stream>>>(
                Q + (size_t)b * sSH, Kb + (size_t)b * sSH, nullptr, nullptr,
                Sc, nullptr, 1 << 30, H, H, H, S, 0, 0, 0, inv_scale);
            softmax_rows<<<dim3(S), g256, 0, stream>>>(Sc, S);
            gemm256<float, 0, true><<<dim3(S / 256, H / 256, 1), g512, 0, stream>>>(
                Sc, Vt + (size_t)b * S, nullptr, nullptr,
                out + (size_t)b * sSH, nullptr, 1 << 30, S, S, B * S, H,
                0, 0, 0, 1.0f);
        }
    }
}

// Round 6
// 328.191 us; speedup vs baseline: 1.0774x; 1.0713x over previous
//
#include <hip/hip_runtime.h>
#include <hip/hip_bf16.h>
#include <stdint.h>

using bf16 = __hip_bfloat16;
typedef __bf16 bf16x8 __attribute__((ext_vector_type(8)));
typedef float f32x4 __attribute__((ext_vector_type(4)));
typedef unsigned short u16x8 __attribute__((ext_vector_type(8)));

#define GLOAD_LDS16(gp, lp)                                                    \
  __builtin_amdgcn_global_load_lds(                                           \
      (const __attribute__((address_space(1))) void*)(gp),                     \
      (__attribute__((address_space(3))) void*)(lp), 16, 0, 0)

#define WAITCNT_VM0() asm volatile("s_waitcnt vmcnt(0)" ::: "memory")
#define WAITCNT_VM2() asm volatile("s_waitcnt vmcnt(2)" ::: "memory")
#define WAITCNT_LGKM0() asm volatile("s_waitcnt lgkmcnt(0)" ::: "memory")
#define CFENCE() asm volatile("" ::: "memory")
#define BAR() do { CFENCE(); __builtin_amdgcn_s_barrier(); CFENCE(); } while (0)

__device__ inline void store_out(bf16* p, float v)  { *p = __float2bfloat16(v); }
__device__ inline void store_out(float* p, float v) { *p = v; }

// 16 MFMA for one C-quadrant (QM,QN) over K=64 (2 kk-slices). Compile-time
// indices only (rule 20: acc must stay in AGPRs).
template <int QM, int QN>
__device__ __forceinline__ void mfma_q(f32x4 (&acc)[8][4],
                                       const bf16x8 (&AV)[4][2],
                                       const bf16x8 (&BV)[2][2])
{
    #pragma unroll
    for (int kk = 0; kk < 2; ++kk)
        #pragma unroll
        for (int mf = 0; mf < 4; ++mf)
            #pragma unroll
            for (int nf = 0; nf < 2; ++nf)
                acc[QM * 4 + mf][QN * 2 + nf] =
                    __builtin_amdgcn_mfma_f32_16x16x32_bf16(
                        AV[mf][kk], BV[nf][kk],
                        acc[QM * 4 + mf][QN * 2 + nf], 0, 0, 0);
}

// ---------------------------------------------------------------------------
// NT GEMM, 256x256 tile, m201-style 8-phase schedule:
//   BK=64 K-tiles, 2 tiles/iter in a 2-deep LDS double buffer (128 KB),
//   phase = one C-quadrant x K=64 = 16 MFMA; quadrant order (0,0)(0,1)(1,1)(1,0)
//   so per-phase ds_reads are 12/4/8/0 (A and B frags held in regs across
//   phases); 1 half-tile (16 KB, 2 gload_lds/thread) staged per phase;
//   vmcnt(2) ONLY at phases 4 and 8 (T4 counted drain, 10 outstanding -> 8).
// C[m][n] = alpha * sum_k A[m][k]*Bt[n][k] (+bias). 512 thr = 8 waves (2Mx4N),
// per-wave 128x64 out (8x4 frags). Output col-split: cols [0,Nsplit)->out0,
// rest->out1. BIAS_AXIS: 0 per-col, 1 per-row. NFAST: logical tile order for
// T1 XCD chunking. M,N mult of 256; K mult of 128, K/64 >= 4.
//
// LDS layout (elems): buf p at p*32768; A at +0, B at +16384; half h at
// +h*8192. Chunk (16B): chunk_linear(lr,cc) = lr*8 + (cc ^ (lr&7)), lr=row in
// half (0..127), cc=16B-col (0..7). Stage writes chunk idx=t linearly (dst =
// half + t*8 (+4096)), source col pre-swizzled: cc_src=(t&7)^((t>>3)&7).
// Read: elem = lr*64 + ((kk*4+c16)^(fr&7))*8 -> bank-uniform (8 lanes/group).
//
// Stage schedule (iter consumes tiles t=buf0 ph1-4, t+1=buf1 ph5-8):
//   ph1:A1(t+1)  ph2:B0(t+1)  ph3:B1(t+1)  ph4:A0(t+2)
//   ph5:A1(t+2)  ph6:B0(t+2)  ph7:B1(t+2)  ph8:A0(t+3)
// Each target half is dead (last ds_read >= 1 closing barrier earlier):
//   A-halves last read ph3/ph7 (q1), B-halves last read ph2/ph6 (q1; q0 held
//   in regs for ph4/ph8). vmcnt(2)@ph4 lands tile t+1; @ph8 lands tile t+2.
// Tail iter: ph4 vmcnt(0) (only 8 outstanding), ph4-8 stages skipped.
// ---------------------------------------------------------------------------
template <typename OUT_T, int BIAS_AXIS, bool NFAST>
__global__ __launch_bounds__(512, 2) void gemm256(
    const bf16* __restrict__ A, const bf16* __restrict__ Bt,
    const float* __restrict__ bias0, const float* __restrict__ bias1,
    OUT_T* __restrict__ out0, OUT_T* __restrict__ out1, int Nsplit,
    int K, int lda, int ldb, int ldc,
    long long sA, long long sB, long long sC, float alpha)
{
    __shared__ __align__(16) bf16 lds[65536];   // 128 KB

    // T1 chunked XCD swizzle + logical tile decode
    const int Mt = gridDim.x, Nt = gridDim.y;
    const int nwg = Mt * Nt * gridDim.z;
    const int hw  = blockIdx.x + Mt * (blockIdx.y + Nt * blockIdx.z);
    const int lg  = (nwg & 7) ? hw : ((hw & 7) * (nwg >> 3) + (hw >> 3));
    const int per = Mt * Nt;
    const int zt  = lg / per;
    const int rem = lg - zt * per;
    int mt, ntile;
    if (NFAST) { mt = rem / Nt; ntile = rem - mt * Nt; }
    else       { mt = rem % Mt; ntile = rem / Mt; }

    A  += (long long)zt * sA;
    Bt += (long long)zt * sB;
    out0 += (long long)zt * sC;
    if (out1) out1 += (long long)zt * sC;

    const int bm = mt * 256, bn = ntile * 256;
    const int t = threadIdx.x, lane = t & 63;
    const int w = t >> 6, wm = w >> 2, wn = w & 3;
    const int fr = lane & 15, c16 = lane >> 4;

    // staging: thread t stages chunks t and t+512 of each 128x64 half-tile
    const int sr  = t >> 3;                         // row 0..63 (and +64)
    const int scc = ((t & 7) ^ (sr & 7)) << 3;      // pre-swizzled src col
    const bf16* pA = A  + (long long)(bm + sr) * lda + scc;
    const bf16* pB = Bt + (long long)(bn + sr) * ldb + scc;
    const int ldst = t * 8;                         // dst elem in half

#define STAGE_A(HALF, JT, BUFO) do {                                           \
    const bf16* _s = pA + (long long)(HALF) * 128 * lda + (JT) * 64;           \
    GLOAD_LDS16(_s, &lds[(BUFO) + (HALF) * 8192 + ldst]);                      \
    GLOAD_LDS16(_s + 64 * (long long)lda,                                      \
                &lds[(BUFO) + (HALF) * 8192 + ldst + 4096]);                   \
} while (0)
#define STAGE_B(HALF, JT, BUFO) do {                                           \
    const bf16* _s = pB + (long long)(HALF) * 128 * ldb + (JT) * 64;           \
    GLOAD_LDS16(_s, &lds[(BUFO) + 16384 + (HALF) * 8192 + ldst]);              \
    GLOAD_LDS16(_s + 64 * (long long)ldb,                                      \
                &lds[(BUFO) + 16384 + (HALF) * 8192 + ldst + 4096]);           \
} while (0)

    // fragment read addressing (swizzled)
    const int axor0 = ((c16    ) ^ (fr & 7)) << 3;  // kk=0
    const int axor1 = ((c16 + 4) ^ (fr & 7)) << 3;  // kk=1
    const int aoffc = wm * 8192 + fr * 64;
    const int boffc = 16384 + (wn * 64 + fr) * 64;

#define RD(e) (*reinterpret_cast<const bf16x8*>(&lds[(e)]))
#define READ_A(QM, BUFO) do {                                                  \
    _Pragma("unroll") for (int mf = 0; mf < 4; ++mf) {                         \
        aA[mf][0] = RD((BUFO) + aoffc + (QM) * 4096 + mf * 1024 + axor0);      \
        aA[mf][1] = RD((BUFO) + aoffc + (QM) * 4096 + mf * 1024 + axor1);      \
    } } while (0)
#define READ_B(QN, BV, BUFO) do {                                              \
    _Pragma("unroll") for (int nf = 0; nf < 2; ++nf) {                         \
        BV[nf][0] = RD((BUFO) + boffc + (QN) * 2048 + nf * 1024 + axor0);      \
        BV[nf][1] = RD((BUFO) + boffc + (QN) * 2048 + nf * 1024 + axor1);      \
    } } while (0)

    const int nk = K >> 6;          // K-tiles of 64 (even, >= 4)
    const int niter = nk >> 1;

    f32x4 acc[8][4] = {};
    bf16x8 aA[4][2], bQ0[2][2], bQ1[2][2];

    // prologue: tile0 (4 halves) + A0(tile1); drain tile0 (10 -> 2)
    STAGE_A(0, 0, 0); STAGE_A(1, 0, 0); STAGE_B(0, 0, 0); STAGE_B(1, 0, 0);
    STAGE_A(0, 1, 32768);
    WAITCNT_VM2();
    BAR();

    for (int it = 0; it < niter; ++it) {
        const int t2 = it * 2;
        const bool tail = (it == niter - 1);

        // ---- ph1: buf0 q(0,0); reads A(q0) 8 + B(q0) 4
        READ_A(0, 0); READ_B(0, bQ0, 0);
        STAGE_A(1, t2 + 1, 32768);
        BAR(); WAITCNT_LGKM0(); __builtin_amdgcn_sched_barrier(0);
        __builtin_amdgcn_s_setprio(1); mfma_q<0, 0>(acc, aA, bQ0);
        __builtin_amdgcn_s_setprio(0); BAR();

        // ---- ph2: buf0 q(0,1); reads B(q1) 4
        READ_B(1, bQ1, 0);
        STAGE_B(0, t2 + 1, 32768);
        BAR(); WAITCNT_LGKM0(); __builtin_amdgcn_sched_barrier(0);
        __builtin_amdgcn_s_setprio(1); mfma_q<0, 1>(acc, aA, bQ1);
        __builtin_amdgcn_s_setprio(0); BAR();

        // ---- ph3: buf0 q(1,1); reads A(q1) 8
        READ_A(1, 0);
        STAGE_B(1, t2 + 1, 32768);
        BAR(); WAITCNT_LGKM0(); __builtin_amdgcn_sched_barrier(0);
        __builtin_amdgcn_s_setprio(1); mfma_q<1, 1>(acc, aA, bQ1);
        __builtin_amdgcn_s_setprio(0); BAR();

        // ---- ph4: buf0 q(1,0); no reads (A,B in regs); counted vmcnt
        if (!tail) STAGE_A(0, t2 + 2, 0);
        BAR();
        __builtin_amdgcn_s_setprio(1); mfma_q<1, 0>(acc, aA, bQ0);
        __builtin_amdgcn_s_setprio(0);
        if (tail) { WAITCNT_VM0(); } else { WAITCNT_VM2(); }
        BAR();

        // ---- ph5: buf1 q(0,0)
        READ_A(0, 32768); READ_B(0, bQ0, 32768);
        if (!tail) STAGE_A(1, t2 + 2, 0);
        BAR(); WAITCNT_LGKM0(); __builtin_amdgcn_sched_barrier(0);
        __builtin_amdgcn_s_setprio(1); mfma_q<0, 0>(acc, aA, bQ0);
        __builtin_amdgcn_s_setprio(0); BAR();

        // ---- ph6: buf1 q(0,1)
        READ_B(1, bQ1, 32768);
        if (!tail) STAGE_B(0, t2 + 2, 0);
        BAR(); WAITCNT_LGKM0(); __builtin_amdgcn_sched_barrier(0);
        __builtin_amdgcn_s_setprio(1); mfma_q<0, 1>(acc, aA, bQ1);
        __builtin_amdgcn_s_setprio(0); BAR();

        // ---- ph7: buf1 q(1,1)
        READ_A(1, 32768);
        if (!tail) STAGE_B(1, t2 + 2, 0);
        BAR(); WAITCNT_LGKM0(); __builtin_amdgcn_sched_barrier(0);
        __builtin_amdgcn_s_setprio(1); mfma_q<1, 1>(acc, aA, bQ1);
        __builtin_amdgcn_s_setprio(0); BAR();

        // ---- ph8: buf1 q(1,0); no reads; counted vmcnt
        if (!tail) STAGE_A(0, t2 + 3, 32768);
        BAR();
        __builtin_amdgcn_s_setprio(1); mfma_q<1, 0>(acc, aA, bQ0);
        __builtin_amdgcn_s_setprio(0);
        if (!tail) WAITCNT_VM2();
        BAR();
    }

    // ---- epilogue: C/D layout col = lane&15, row = 4*(lane>>4)+reg
    const int colbase = bn + wn * 64 + fr;
    const int rowbase = bm + wm * 128 + c16 * 4;
    #pragma unroll
    for (int n = 0; n < 4; ++n) {
        const int gc = colbase + n * 16;
        const bool seg0 = gc < Nsplit;
        OUT_T* op = seg0 ? out0 : out1;
        const int col = seg0 ? gc : gc - Nsplit;
        float bcol = 0.0f;
        if (BIAS_AXIS == 0) {
            const float* bp = seg0 ? bias0 : bias1;
            if (bp) bcol = bp[col];
        }
        #pragma unroll
        for (int m = 0; m < 8; ++m) {
            #pragma unroll
            for (int jj = 0; jj < 4; ++jj) {
                const int row = rowbase + m * 16 + jj;
                float v = acc[m][n][jj] * alpha;
                if (BIAS_AXIS == 0) v += bcol;
                else if (bias0)     v += bias0[row];
                store_out(&op[(long long)row * ldc + col], v);
            }
        }
    }
#undef STAGE_A
#undef STAGE_B
#undef RD
#undef READ_A
#undef READ_B
}

// ---------------------------------------------------------------------------
__global__ __launch_bounds__(256) void f32_to_bf16(
    const float* __restrict__ in, bf16* __restrict__ out, long long n)
{
    long long i = ((long long)blockIdx.x * 256 + threadIdx.x) * 4;
    const long long stride = (long long)gridDim.x * 256 * 4;
    for (; i < n; i += stride) {
        float4 v = *reinterpret_cast<const float4*>(in + i);
        unsigned ux = __float_as_uint(v.x), uy = __float_as_uint(v.y);
        unsigned uz = __float_as_uint(v.z), uw = __float_as_uint(v.w);
        ushort4 o;
        o.x = (unsigned short)((ux + 0x7fffu + ((ux >> 16) & 1u)) >> 16);
        o.y = (unsigned short)((uy + 0x7fffu + ((uy >> 16) & 1u)) >> 16);
        o.z = (unsigned short)((uz + 0x7fffu + ((uz >> 16) & 1u)) >> 16);
        o.w = (unsigned short)((uw + 0x7fffu + ((uw >> 16) & 1u)) >> 16);
        *reinterpret_cast<ushort4*>(out + i) = o;
    }
}

__global__ void transpose_f32_bf16(const float* __restrict__ in,
                                   bf16* __restrict__ out, int R, int C)
{
    __shared__ float tile[32][33];
    const int c0 = blockIdx.x * 32, r0 = blockIdx.y * 32;
    const int tx = threadIdx.x, ty = threadIdx.y;
    #pragma unroll
    for (int i = ty; i < 32; i += 8)
        tile[i][tx] = in[(long long)(r0 + i) * C + (c0 + tx)];
    __syncthreads();
    #pragma unroll
    for (int i = ty; i < 32; i += 8)
        out[(long long)(c0 + i) * R + (r0 + tx)] = __float2bfloat16(tile[tx][i]);
}

__global__ __launch_bounds__(256) void softmax_rows(bf16* __restrict__ Sbuf, int cols)
{
    __shared__ float red[8];
    bf16* p = Sbuf + (long long)blockIdx.x * cols;
    const int t = threadIdx.x;

    u16x8 v = *reinterpret_cast<const u16x8*>(p + t * 8);
    float f[8];
    #pragma unroll
    for (int i = 0; i < 8; ++i)
        f[i] = __uint_as_float((unsigned)v[i] << 16);

    float m = -3.0e38f;
    #pragma unroll
    for (int i = 0; i < 8; ++i) m = fmaxf(m, f[i]);
    #pragma unroll
    for (int o = 32; o; o >>= 1) m = fmaxf(m, __shfl_xor(m, o));
    if ((t & 63) == 0) red[t >> 6] = m;
    __syncthreads();
    m = fmaxf(fmaxf(red[0], red[1]), fmaxf(red[2], red[3]));

    float s = 0.0f;
    #pragma unroll
    for (int i = 0; i < 8; ++i) { f[i] = __expf(f[i] - m); s += f[i]; }
    #pragma unroll
    for (int o = 32; o; o >>= 1) s += __shfl_xor(s, o);
    __syncthreads();
    if ((t & 63) == 0) red[4 + (t >> 6)] = s;
    __syncthreads();
    s = (red[4] + red[5]) + (red[6] + red[7]);
    const float inv = 1.0f / s;

    u16x8 o16;
    #pragma unroll
    for (int i = 0; i < 8; ++i) {
        unsigned u = __float_as_uint(f[i] * inv);
        o16[i] = (unsigned short)((u + 0x7fffu + ((u >> 16) & 1u)) >> 16);  // RNE
    }
    *reinterpret_cast<u16x8*>(p + t * 8) = o16;
}

// ---------------------------------------------------------------------------
extern "C" void kernel_launch(void* const* d_in, const int* in_sizes, int n_in,
                              void* d_out, int out_size, void* d_ws, size_t ws_size,
                              hipStream_t stream)
{
    const int B = 8, S = 2048, D = 1024, H = 1024;
    const float* x  = (const float*)d_in[0];
    const float* Wq = (const float*)d_in[1];
    const float* bq = (const float*)d_in[2];
    const float* Wk = (const float*)d_in[3];
    const float* bk = (const float*)d_in[4];
    const float* Wv = (const float*)d_in[5];
    const float* bv = (const float*)d_in[6];
    float* out = (float*)d_out;

    const size_t nQKV = (size_t)B * S * H;
    const size_t nW   = (size_t)D * H;
    const long long sSH = (long long)S * H;
    const long long sSS = (long long)S * S;

    dim3 tb(32, 8), g256(256), g512(512);
    const float inv_scale = 1.0f / 32.0f;

    bf16* xb   = (bf16*)d_ws;
    bf16* Q    = xb  + nQKV;
    bf16* Kb   = Q   + nQKV;
    bf16* Vt   = Kb  + nQKV;                 // [H][B*S]
    bf16* WtQK = Vt  + nQKV;
    bf16* Wtv  = WtQK + 2 * nW;
    bf16* Sc   = Wtv + nW;

    const size_t tierA = (4 * nQKV + 3 * nW + (size_t)B * S * S) * 2;
    const size_t tierB = (4 * nQKV + 3 * nW + (size_t)S * S) * 2;
    const bool bigA = ws_size >= tierA;
    if (ws_size < tierB) return;

    f32_to_bf16<<<dim3(2048), g256, 0, stream>>>(x, xb, (long long)nQKV);
    transpose_f32_bf16<<<dim3(H / 32, D / 32), tb, 0, stream>>>(Wq, WtQK, D, H);
    transpose_f32_bf16<<<dim3(H / 32, D / 32), tb, 0, stream>>>(Wk, WtQK + nW, D, H);
    transpose_f32_bf16<<<dim3(H / 32, D / 32), tb, 0, stream>>>(Wv, Wtv, D, H);

    // fused Q|K projection
    gemm256<bf16, 0, true><<<dim3(B * S / 256, 2 * H / 256, 1), g512, 0, stream>>>(
        xb, WtQK, bq, bk, Q, Kb, H, D, D, D, H, 0, 0, 0, 1.0f);

    // V^T = Wv^T x^T (bias per-row)
    gemm256<bf16, 1, false><<<dim3(H / 256, B * S / 256, 1), g512, 0, stream>>>(
        Wtv, xb, bv, nullptr, Vt, nullptr, 1 << 30, D, D, D, B * S, 0, 0, 0, 1.0f);

    if (bigA) {
        gemm256<bf16, 0, true><<<dim3(S / 256, S / 256, B), g512, 0, stream>>>(
            Q, Kb, nullptr, nullptr, Sc, nullptr, 1 << 30, H, H, H, S,
            sSH, sSH, sSS, inv_scale);
        softmax_rows<<<dim3(B * S), g256, 0, stream>>>(Sc, S);
        gemm256<float, 0, true><<<dim3(S / 256, H / 256, B), g512, 0, stream>>>(
            Sc, Vt, nullptr, nullptr, out, nullptr, 1 << 30, S, S, B * S, H,
            sSS, (long long)S, sSH, 1.0f);
    } else {
        for (int b = 0; b < B; ++b) {
            gemm256<bf16, 0, true><<<dim3(S / 256, S / 256, 1), g512, 0, stream>>>(
                Q + (size_t)b * sSH, Kb + (size_t)b * sSH, nullptr, nullptr,
                Sc, nullptr, 1 << 30, H, H, H, S, 0, 0, 0, inv_scale);
            softmax_rows<<<dim3(S), g256, 0, stream>>>(Sc, S);
            gemm256<float, 0, true><<<dim3(S / 256, H / 256, 1), g512, 0, stream>>>(
                Sc, Vt + (size_t)b * S, nullptr, nullptr,
                out + (size_t)b * sSH, nullptr, 1 << 30, S, S, B * S, H,
                0, 0, 0, 1.0f);
        }
    }
}